// Round 3
// baseline (248.374 us; speedup 1.0000x reference)
//
#include <hip/hip_runtime.h>
#include <math.h>

// Problem constants (B,S,D,H) = (8, 2048, 1024, 4), HD = 256
#define BB 8
#define SS 2048
#define DD 1024
#define HH 4
#define HDD 256
#define NROW (BB*SS)           // 16384

// ---------------- fused (cooperative) config ----------------
#define GG 32                  // rows per block
#define NBLK (NROW/GG)         // 512 blocks -> 2 blocks/CU co-resident

// fused ws layout (float offsets): only accumulators + flags (~66 KB)
#define OFF_TG    0                    // [B][D] sum of text_rep over S
#define OFF_IG    (BB*DD)              // [B][D]
#define OFF_SIM   (2*BB*DD)            // [B]
#define OFF_LOGIT (OFF_SIM + BB)       // [B]
#define OFF_CNT   (OFF_LOGIT + BB)     // 2 ints (c1, c2)
#define WS_CLEAR  (OFF_CNT + 2)

// ---------------- fallback chain config (proven 241.6us) ----------------
#define GF 8
#define NSLF (NROW/GF)         // 2048
#define F_MU_T 0
#define F_RS_T NROW
#define F_MU_I (2*NROW)
#define F_RS_I (3*NROW)
#define F_PT   (4*NROW)
#define F_PI   (F_PT + NSLF*DD)
#define F_PS   (F_PI + NSLF*DD)
#define F_TG   (F_PS + NSLF)
#define F_IG   (F_TG + BB*DD)
#define F_SIM  (F_IG + BB*DD)
#define F_LOGIT (F_SIM + BB)

__device__ __forceinline__ float wred(float v) {
#pragma unroll
  for (int m = 32; m > 0; m >>= 1) v += __shfl_xor(v, m, 64);
  return v;
}
__device__ __forceinline__ float hsum(const float4 v) { return v.x+v.y+v.z+v.w; }
__device__ __forceinline__ float hsq(const float4 v)  { return v.x*v.x+v.y*v.y+v.z*v.z+v.w*v.w; }
__device__ __forceinline__ float hdot(const float4 a, const float4 b) {
  return a.x*b.x + a.y*b.y + a.z*b.z + a.w*b.w;
}

// =====================================================================
// Fused cooperative kernel, custom lightweight barriers.
//   Phase 1 (all 512 blocks): wave-per-row stats (prefetched), LDS-combine,
//            atomicAdd into TG/IG/SIM.  arrive c1.
//   Gates  (blocks 0..255): spin c1==512, fence, dot TG/IG with Wa/Wq,
//            atomicAdd LOGIT.  arrive c2.
//   Blend  (all blocks): spin c2==256, fence, sigmoid(logit), blend own
//            32 rows using LDS-resident mu/rs.  No cg::grid.sync anywhere.
// =====================================================================
__global__ __launch_bounds__(256, 2) void fused(
    const float* __restrict__ text, const float* __restrict__ image,
    const float* __restrict__ wt, const float* __restrict__ bt,
    const float* __restrict__ wi, const float* __restrict__ bi,
    const float* __restrict__ Wa, const float* __restrict__ Wab,
    const float* __restrict__ Wq, const float* __restrict__ Wqb,
    const float* __restrict__ simw, const float* __restrict__ simb,
    const float* __restrict__ fcw, const float* __restrict__ fcb,
    float* __restrict__ ws, float* __restrict__ out)
{
  const int blk  = blockIdx.x;
  const int tid  = threadIdx.x;
  const int lane = tid & 63;
  const int wv   = tid >> 6;
  const int row0 = blk * GG;
  const int b    = blk >> 6;           // 64 blocks per batch

  __shared__ float smu_t[GG], srs_t[GG], smu_i[GG], srs_i[GG];
  __shared__ float sAcc[2][4][DD];     // 32 KB: per-wave global partial combine
  __shared__ float ssim[4];
  __shared__ float red3[4][4][BB];     // gates

  int* c1 = (int*)(ws + OFF_CNT);
  int* c2 = c1 + 1;

  // ---------------- Phase 1: wave-per-row stats, prefetched ----------------
  {
    const int cb = lane << 2;          // col base within each 256-col chunk
    float4 Wt[4], Bt[4], Wi4[4], Bi4[4];
#pragma unroll
    for (int j = 0; j < 4; ++j) {
      Wt[j]  = *(const float4*)(wt + j*256 + cb);
      Bt[j]  = *(const float4*)(bt + j*256 + cb);
      Wi4[j] = *(const float4*)(wi + j*256 + cb);
      Bi4[j] = *(const float4*)(bi + j*256 + cb);
    }
    float4 tga[4], iga[4];
#pragma unroll
    for (int j = 0; j < 4; ++j) {
      tga[j] = make_float4(0.f,0.f,0.f,0.f);
      iga[j] = make_float4(0.f,0.f,0.f,0.f);
    }
    float sim_loc = 0.f;
    const float invD = 1.f/DD;
    const int rbase = row0 + wv*8;     // this wave's 8 rows

    float4 tb[2][4], ib[2][4];         // double-buffered row registers
    {
      const float* tr = text  + (size_t)rbase*DD + cb;
      const float* ir = image + (size_t)rbase*DD + cb;
#pragma unroll
      for (int j = 0; j < 4; ++j) {
        tb[0][j] = *(const float4*)(tr + j*256);
        ib[0][j] = *(const float4*)(ir + j*256);
      }
    }

#pragma unroll 2
    for (int r = 0; r < 8; ++r) {
      const int cur = r & 1, nxt = cur ^ 1;   // compile-time after unroll 2
      if (r < 7) {                     // prefetch next row under this row's work
        const float* tr = text  + (size_t)(rbase + r + 1)*DD + cb;
        const float* ir = image + (size_t)(rbase + r + 1)*DD + cb;
#pragma unroll
        for (int j = 0; j < 4; ++j) {
          tb[nxt][j] = *(const float4*)(tr + j*256);
          ib[nxt][j] = *(const float4*)(ir + j*256);
        }
      }

      float st=0.f, qt=0.f, si=0.f, qi=0.f;
#pragma unroll
      for (int j = 0; j < 4; ++j) {
        st += hsum(tb[cur][j]);  qt += hsq(tb[cur][j]);
        si += hsum(ib[cur][j]);  qi += hsq(ib[cur][j]);
      }
      st = wred(st); qt = wred(qt); si = wred(si); qi = wred(qi);
      const float mt = st*invD, rt = rsqrtf(qt*invD - mt*mt + 1e-5f);
      const float mi = si*invD, ri = rsqrtf(qi*invD - mi*mi + 1e-5f);
      if (lane == 0) {
        smu_t[wv*8+r]=mt; srs_t[wv*8+r]=rt;
        smu_i[wv*8+r]=mi; srs_i[wv*8+r]=ri;
      }

      float dot=0.f, nt=0.f, ni=0.f;
#pragma unroll
      for (int j = 0; j < 4; ++j) {
        float4 tn, iv;
        tn.x = (tb[cur][j].x-mt)*rt*Wt[j].x + Bt[j].x;
        tn.y = (tb[cur][j].y-mt)*rt*Wt[j].y + Bt[j].y;
        tn.z = (tb[cur][j].z-mt)*rt*Wt[j].z + Bt[j].z;
        tn.w = (tb[cur][j].w-mt)*rt*Wt[j].w + Bt[j].w;
        iv.x = (ib[cur][j].x-mi)*ri*Wi4[j].x + Bi4[j].x;
        iv.y = (ib[cur][j].y-mi)*ri*Wi4[j].y + Bi4[j].y;
        iv.z = (ib[cur][j].z-mi)*ri*Wi4[j].z + Bi4[j].z;
        iv.w = (ib[cur][j].w-mi)*ri*Wi4[j].w + Bi4[j].w;
        tga[j].x += tn.x; tga[j].y += tn.y; tga[j].z += tn.z; tga[j].w += tn.w;
        iga[j].x += iv.x; iga[j].y += iv.y; iga[j].z += iv.z; iga[j].w += iv.w;
        dot += hdot(tn, iv); nt += hsq(tn); ni += hsq(iv);
      }
      dot = wred(dot); nt = wred(nt); ni = wred(ni);
      sim_loc += dot / (fmaxf(sqrtf(nt),1e-6f) * fmaxf(sqrtf(ni),1e-6f));
    }

    // Block-combine per-wave global partials in LDS, then atomics into TG/IG.
#pragma unroll
    for (int j = 0; j < 4; ++j) {
      *(float4*)&sAcc[0][wv][j*256 + cb] = tga[j];
      *(float4*)&sAcc[1][wv][j*256 + cb] = iga[j];
    }
    if (lane == 0) ssim[wv] = sim_loc;
    __syncthreads();

    const int c0 = tid << 2;
    float4 vt = make_float4(0.f,0.f,0.f,0.f);
    float4 vi = make_float4(0.f,0.f,0.f,0.f);
#pragma unroll
    for (int w = 0; w < 4; ++w) {
      const float4 a = *(const float4*)&sAcc[0][w][c0];
      vt.x += a.x; vt.y += a.y; vt.z += a.z; vt.w += a.w;
      const float4 e = *(const float4*)&sAcc[1][w][c0];
      vi.x += e.x; vi.y += e.y; vi.z += e.z; vi.w += e.w;
    }
    atomicAdd(&ws[OFF_TG + b*DD + c0 + 0], vt.x);
    atomicAdd(&ws[OFF_TG + b*DD + c0 + 1], vt.y);
    atomicAdd(&ws[OFF_TG + b*DD + c0 + 2], vt.z);
    atomicAdd(&ws[OFF_TG + b*DD + c0 + 3], vt.w);
    atomicAdd(&ws[OFF_IG + b*DD + c0 + 0], vi.x);
    atomicAdd(&ws[OFF_IG + b*DD + c0 + 1], vi.y);
    atomicAdd(&ws[OFF_IG + b*DD + c0 + 2], vi.z);
    atomicAdd(&ws[OFF_IG + b*DD + c0 + 3], vi.w);
    if (tid == 0) {
      atomicAdd(&ws[OFF_SIM + b], ssim[0]+ssim[1]+ssim[2]+ssim[3]);
    }
  }

  // Arrival: atomics drained by the barrier before signaling.
  __syncthreads();
  if (tid == 0) {
    __hip_atomic_fetch_add(c1, 1, __ATOMIC_RELEASE, __HIP_MEMORY_SCOPE_AGENT);
  }

  // ---------------- Gates (blocks 0..255) ----------------
  if (blk < 256) {
    if (tid == 0) {
      while (__hip_atomic_load(c1, __ATOMIC_RELAXED, __HIP_MEMORY_SCOPE_AGENT) < NBLK)
        __builtin_amdgcn_s_sleep(8);
      __threadfence();                 // acquire: invalidate caches, see atomics
    }
    __syncthreads();

    const int d0 = tid << 2;
    const int r0 = blk * 4;            // flat (h,k) row base, 0..1023
    for (int rr = 0; rr < 4; ++rr) {
      const int r = r0 + rr;
      const float4 a4 = *(const float4*)(Wa + (size_t)r*DD + d0);
      const float4 q4 = *(const float4*)(Wq + (size_t)r*DD + d0);
      float acc[BB];
#pragma unroll
      for (int bq = 0; bq < BB; ++bq) {
        const float4 t = *(const float4*)(ws + OFF_TG + bq*DD + d0);
        const float4 i = *(const float4*)(ws + OFF_IG + bq*DD + d0);
        acc[bq] = hdot(a4, t) + hdot(q4, i);
      }
#pragma unroll
      for (int bq = 0; bq < BB; ++bq) {
        acc[bq] = wred(acc[bq]);
        if (lane == 0) red3[rr][wv][bq] = acc[bq];
      }
    }
    __syncthreads();
    if (tid < BB) {
      const int bq = tid;
      const float inv = 1.f/SS;
      const float gs = ws[OFF_SIM + bq] * inv;
      float part = 0.f;
#pragma unroll
      for (int rr = 0; rr < 4; ++rr) {
        const int r = r0 + rr;
        const int k = r & 255;
        const float v = (red3[rr][0][bq] + red3[rr][1][bq] + red3[rr][2][bq] + red3[rr][3][bq]) * inv;
        float gate = v + Wab[r] + Wqb[r] + gs*simw[k] + simb[k];
        gate = fmaxf(gate, 0.f);
        part += gate * fcw[r];
      }
      atomicAdd(&ws[OFF_LOGIT + bq], part);
    }
    __syncthreads();                   // drain LOGIT atomics of tid 0..7
    if (tid == 0) {
      __hip_atomic_fetch_add(c2, 1, __ATOMIC_RELEASE, __HIP_MEMORY_SCOPE_AGENT);
    }
  }

  // ---------------- Blend (all blocks) ----------------
  if (tid == 0) {
    while (__hip_atomic_load(c2, __ATOMIC_RELAXED, __HIP_MEMORY_SCOPE_AGENT) < 256)
      __builtin_amdgcn_s_sleep(8);
    __threadfence();                   // acquire: LOGIT visible
  }
  __syncthreads();

  {
    const int d0 = tid << 2;
    const float4 wt4 = *(const float4*)(wt + d0);
    const float4 bt4 = *(const float4*)(bt + d0);
    const float4 wi4 = *(const float4*)(wi + d0);
    const float4 bi4 = *(const float4*)(bi + d0);
    const float g  = 1.f / (1.f + expf(-(ws[OFF_LOGIT + b] + fcb[0])));
    const float gi = 1.f - g;

    float4 tg[2][4], ig[2][4];         // double-buffered 4-row groups
#pragma unroll
    for (int r = 0; r < 4; ++r) {
      tg[0][r] = *(const float4*)(text  + (size_t)(row0+r)*DD + d0);
      ig[0][r] = *(const float4*)(image + (size_t)(row0+r)*DD + d0);
    }
#pragma unroll 2
    for (int gidx = 0; gidx < 8; ++gidx) {
      const int cur = gidx & 1, nxt = cur ^ 1;
      if (gidx < 7) {
        const int nr = row0 + (gidx+1)*4;
#pragma unroll
        for (int r = 0; r < 4; ++r) {
          tg[nxt][r] = *(const float4*)(text  + (size_t)(nr+r)*DD + d0);
          ig[nxt][r] = *(const float4*)(image + (size_t)(nr+r)*DD + d0);
        }
      }
      const int rr = gidx*4;
#pragma unroll
      for (int r = 0; r < 4; ++r) {
        const float mt = smu_t[rr+r], rt = srs_t[rr+r];
        const float mi = smu_i[rr+r], ri = srs_i[rr+r];
        const float gt = g*rt, gii = gi*ri;
        float4 o;
        o.x = gt*(tg[cur][r].x-mt)*wt4.x + g*bt4.x + gii*(ig[cur][r].x-mi)*wi4.x + gi*bi4.x;
        o.y = gt*(tg[cur][r].y-mt)*wt4.y + g*bt4.y + gii*(ig[cur][r].y-mi)*wi4.y + gi*bi4.y;
        o.z = gt*(tg[cur][r].z-mt)*wt4.z + g*bt4.z + gii*(ig[cur][r].z-mi)*wi4.z + gi*bi4.z;
        o.w = gt*(tg[cur][r].w-mt)*wt4.w + g*bt4.w + gii*(ig[cur][r].w-mi)*wi4.w + gi*bi4.w;
        *(float4*)(out + (size_t)(row0+rr+r)*DD + d0) = o;
      }
    }
  }
}

// =====================================================================
// Fallback chain (proven 241.6 us) — only used if coop launch fails.
// =====================================================================
__global__ __launch_bounds__(256) void k1_stats(
    const float* __restrict__ text, const float* __restrict__ image,
    const float* __restrict__ wt, const float* __restrict__ bt,
    const float* __restrict__ wi, const float* __restrict__ bi,
    float* __restrict__ ws)
{
  const int g    = blockIdx.x;
  const int tid  = threadIdx.x;
  const int lane = tid & 63;
  const int wv   = tid >> 6;
  const int d0   = tid << 2;
  const int row0 = g * GF;

  __shared__ float red1[4][8];
  __shared__ float red2[4][6];

  const float4 wt4 = *(const float4*)(wt + d0);
  const float4 bt4 = *(const float4*)(bt + d0);
  const float4 wi4 = *(const float4*)(wi + d0);
  const float4 bi4 = *(const float4*)(bi + d0);

  float4 tga = make_float4(0.f,0.f,0.f,0.f);
  float4 iga = make_float4(0.f,0.f,0.f,0.f);
  float sim_loc = 0.f;

  for (int r = 0; r < GF; r += 2) {
    const size_t base0 = (size_t)(row0 + r) * DD + d0;
    const size_t base1 = base0 + DD;
    const float4 t0 = *(const float4*)(text  + base0);
    const float4 i0 = *(const float4*)(image + base0);
    const float4 t1 = *(const float4*)(text  + base1);
    const float4 i1 = *(const float4*)(image + base1);

    float a0 = hsum(t0), a1 = hsq(t0), a2 = hsum(i0), a3 = hsq(i0);
    float a4 = hsum(t1), a5 = hsq(t1), a6 = hsum(i1), a7 = hsq(i1);
    a0 = wred(a0); a1 = wred(a1); a2 = wred(a2); a3 = wred(a3);
    a4 = wred(a4); a5 = wred(a5); a6 = wred(a6); a7 = wred(a7);
    if (lane == 0) {
      red1[wv][0]=a0; red1[wv][1]=a1; red1[wv][2]=a2; red1[wv][3]=a3;
      red1[wv][4]=a4; red1[wv][5]=a5; red1[wv][6]=a6; red1[wv][7]=a7;
    }
    __syncthreads();
    float s[8];
#pragma unroll
    for (int q = 0; q < 8; ++q) s[q] = red1[0][q]+red1[1][q]+red1[2][q]+red1[3][q];
    const float invD = 1.f/DD;
    const float mt0 = s[0]*invD, rt0 = rsqrtf(s[1]*invD - mt0*mt0 + 1e-5f);
    const float mi0 = s[2]*invD, ri0 = rsqrtf(s[3]*invD - mi0*mi0 + 1e-5f);
    const float mt1 = s[4]*invD, rt1 = rsqrtf(s[5]*invD - mt1*mt1 + 1e-5f);
    const float mi1 = s[6]*invD, ri1 = rsqrtf(s[7]*invD - mi1*mi1 + 1e-5f);
    if (tid == 0) {
      const int row = row0 + r;
      ws[F_MU_T+row]=mt0;   ws[F_RS_T+row]=rt0;
      ws[F_MU_I+row]=mi0;   ws[F_RS_I+row]=ri0;
      ws[F_MU_T+row+1]=mt1; ws[F_RS_T+row+1]=rt1;
      ws[F_MU_I+row+1]=mi1; ws[F_RS_I+row+1]=ri1;
    }
    float4 tn0, in0, tn1, in1;
    tn0.x = (t0.x-mt0)*rt0*wt4.x + bt4.x;  tn0.y = (t0.y-mt0)*rt0*wt4.y + bt4.y;
    tn0.z = (t0.z-mt0)*rt0*wt4.z + bt4.z;  tn0.w = (t0.w-mt0)*rt0*wt4.w + bt4.w;
    in0.x = (i0.x-mi0)*ri0*wi4.x + bi4.x;  in0.y = (i0.y-mi0)*ri0*wi4.y + bi4.y;
    in0.z = (i0.z-mi0)*ri0*wi4.z + bi4.z;  in0.w = (i0.w-mi0)*ri0*wi4.w + bi4.w;
    tn1.x = (t1.x-mt1)*rt1*wt4.x + bt4.x;  tn1.y = (t1.y-mt1)*rt1*wt4.y + bt4.y;
    tn1.z = (t1.z-mt1)*rt1*wt4.z + bt4.z;  tn1.w = (t1.w-mt1)*rt1*wt4.w + bt4.w;
    in1.x = (i1.x-mi1)*ri1*wi4.x + bi4.x;  in1.y = (i1.y-mi1)*ri1*wi4.y + bi4.y;
    in1.z = (i1.z-mi1)*ri1*wi4.z + bi4.z;  in1.w = (i1.w-mi1)*ri1*wi4.w + bi4.w;

    tga.x += tn0.x + tn1.x; tga.y += tn0.y + tn1.y;
    tga.z += tn0.z + tn1.z; tga.w += tn0.w + tn1.w;
    iga.x += in0.x + in1.x; iga.y += in0.y + in1.y;
    iga.z += in0.z + in1.z; iga.w += in0.w + in1.w;

    float b0 = hdot(tn0,in0), b1 = hsq(tn0), b2 = hsq(in0);
    float b3 = hdot(tn1,in1), b4 = hsq(tn1), b5 = hsq(in1);
    b0 = wred(b0); b1 = wred(b1); b2 = wred(b2);
    b3 = wred(b3); b4 = wred(b4); b5 = wred(b5);
    if (lane == 0) {
      red2[wv][0]=b0; red2[wv][1]=b1; red2[wv][2]=b2;
      red2[wv][3]=b3; red2[wv][4]=b4; red2[wv][5]=b5;
    }
    __syncthreads();
    if (tid == 0) {
      float u[6];
#pragma unroll
      for (int q = 0; q < 6; ++q) u[q] = red2[0][q]+red2[1][q]+red2[2][q]+red2[3][q];
      sim_loc += u[0] / (fmaxf(sqrtf(u[1]),1e-6f) * fmaxf(sqrtf(u[2]),1e-6f));
      sim_loc += u[3] / (fmaxf(sqrtf(u[4]),1e-6f) * fmaxf(sqrtf(u[5]),1e-6f));
    }
  }
  *(float4*)(ws + F_PT + (size_t)g*DD + d0) = tga;
  *(float4*)(ws + F_PI + (size_t)g*DD + d0) = iga;
  if (tid == 0) ws[F_PS + g] = sim_loc;
}

__global__ __launch_bounds__(256) void kR_reduce(float* __restrict__ ws)
{
  const int tid = threadIdx.x;
  if (blockIdx.x < 256) {
    const int b   = blockIdx.x >> 5;
    const int ch  = blockIdx.x & 31;
    const int cl  = tid & 31;
    const int sg  = tid >> 5;
    const int col = ch*32 + cl;
    const float* pt = ws + F_PT + (size_t)(b*256 + sg*32)*DD + col;
    const float* pi = ws + F_PI + (size_t)(b*256 + sg*32)*DD + col;
    float at = 0.f, ai = 0.f;
#pragma unroll 4
    for (int k = 0; k < 32; ++k) {
      at += pt[(size_t)k*DD];
      ai += pi[(size_t)k*DD];
    }
    __shared__ float sred[2][8][32];
    sred[0][sg][cl] = at;
    sred[1][sg][cl] = ai;
    __syncthreads();
    if (tid < 32) {
      float v = 0.f;
#pragma unroll
      for (int q = 0; q < 8; ++q) v += sred[0][q][tid];
      ws[F_TG + b*DD + ch*32 + tid] = v;
    } else if (tid < 64) {
      const int c = tid - 32;
      float v = 0.f;
#pragma unroll
      for (int q = 0; q < 8; ++q) v += sred[1][q][c];
      ws[F_IG + b*DD + ch*32 + c] = v;
    }
  } else {
    __shared__ float sred[256];
    const int b = tid >> 5, j = tid & 31;
    float a = 0.f;
#pragma unroll
    for (int k = 0; k < 8; ++k) a += ws[F_PS + b*256 + j*8 + k];
    sred[tid] = a;
    __syncthreads();
    if (j == 0) {
      float s = 0.f;
#pragma unroll
      for (int m = 0; m < 32; ++m) s += sred[b*32 + m];
      ws[F_SIM + b] = s;
    }
    if (tid < BB) ws[F_LOGIT + tid] = 0.f;
  }
}

__global__ __launch_bounds__(256) void k2_gates(
    const float* __restrict__ Wa, const float* __restrict__ Wab,
    const float* __restrict__ Wq, const float* __restrict__ Wqb,
    const float* __restrict__ simw, const float* __restrict__ simb,
    const float* __restrict__ fcw, float* __restrict__ ws)
{
  const int tid  = threadIdx.x;
  const int lane = tid & 63;
  const int wv   = tid >> 6;
  const int r0   = blockIdx.x * 4;
  const int d0   = tid << 2;

  __shared__ float red[4][4][BB];

  for (int rr = 0; rr < 4; ++rr) {
    const int r = r0 + rr;
    const float4 a4 = *(const float4*)(Wa + (size_t)r*DD + d0);
    const float4 q4 = *(const float4*)(Wq + (size_t)r*DD + d0);
    float acc[BB];
#pragma unroll
    for (int b = 0; b < BB; ++b) {
      const float4 t = *(const float4*)(ws + F_TG + b*DD + d0);
      const float4 i = *(const float4*)(ws + F_IG + b*DD + d0);
      acc[b] = hdot(a4, t) + hdot(q4, i);
    }
#pragma unroll
    for (int b = 0; b < BB; ++b) {
      acc[b] = wred(acc[b]);
      if (lane == 0) red[rr][wv][b] = acc[b];
    }
  }
  __syncthreads();
  if (tid < BB) {
    const int b = tid;
    const float inv = 1.f/SS;
    const float gs = ws[F_SIM + b] * inv;
    float part = 0.f;
#pragma unroll
    for (int rr = 0; rr < 4; ++rr) {
      const int r = r0 + rr;
      const int k = r & 255;
      const float v = (red[rr][0][b] + red[rr][1][b] + red[rr][2][b] + red[rr][3][b]) * inv;
      float gate = v + Wab[r] + Wqb[r] + gs*simw[k] + simb[k];
      gate = fmaxf(gate, 0.f);
      part += gate * fcw[r];
    }
    atomicAdd(&ws[F_LOGIT + b], part);
  }
}

__global__ __launch_bounds__(256) void k3_blend(
    const float* __restrict__ text, const float* __restrict__ image,
    const float* __restrict__ wt, const float* __restrict__ bt,
    const float* __restrict__ wi, const float* __restrict__ bi,
    const float* __restrict__ fcb,
    const float* __restrict__ ws, float* __restrict__ out)
{
  const int r0 = blockIdx.x * 4;
  const int b  = r0 >> 11;
  const int d0 = threadIdx.x << 2;

  float4 t[4], im[4];
#pragma unroll
  for (int r = 0; r < 4; ++r) {
    t[r]  = *(const float4*)(text  + (size_t)(r0+r)*DD + d0);
    im[r] = *(const float4*)(image + (size_t)(r0+r)*DD + d0);
  }
  const float4 wt4 = *(const float4*)(wt + d0);
  const float4 bt4 = *(const float4*)(bt + d0);
  const float4 wi4 = *(const float4*)(wi + d0);
  const float4 bi4 = *(const float4*)(bi + d0);

  const float g  = 1.f / (1.f + expf(-(ws[F_LOGIT+b] + fcb[0])));
  const float gi = 1.f - g;

#pragma unroll
  for (int r = 0; r < 4; ++r) {
    const float mt = ws[F_MU_T+r0+r], rt = ws[F_RS_T+r0+r];
    const float mi = ws[F_MU_I+r0+r], ri = ws[F_RS_I+r0+r];
    const float gt = g*rt, gii = gi*ri;
    float4 o;
    o.x = gt*(t[r].x-mt)*wt4.x + g*bt4.x + gii*(im[r].x-mi)*wi4.x + gi*bi4.x;
    o.y = gt*(t[r].y-mt)*wt4.y + g*bt4.y + gii*(im[r].y-mi)*wi4.y + gi*bi4.y;
    o.z = gt*(t[r].z-mt)*wt4.z + g*bt4.z + gii*(im[r].z-mi)*wi4.z + gi*bi4.z;
    o.w = gt*(t[r].w-mt)*wt4.w + g*bt4.w + gii*(im[r].w-mi)*wi4.w + gi*bi4.w;
    *(float4*)(out + (size_t)(r0+r)*DD + d0) = o;
  }
}

extern "C" void kernel_launch(void* const* d_in, const int* in_sizes, int n_in,
                              void* d_out, int out_size, void* d_ws, size_t ws_size,
                              hipStream_t stream)
{
  const float* text   = (const float*)d_in[0];
  const float* image  = (const float*)d_in[1];
  const float* ln_t_w = (const float*)d_in[2];
  const float* ln_t_b = (const float*)d_in[3];
  const float* ln_i_w = (const float*)d_in[4];
  const float* ln_i_b = (const float*)d_in[5];
  const float* Wa     = (const float*)d_in[6];
  const float* Wab    = (const float*)d_in[7];
  const float* Wq     = (const float*)d_in[8];
  const float* Wqb    = (const float*)d_in[9];
  const float* simw   = (const float*)d_in[10];
  const float* simb   = (const float*)d_in[11];
  const float* fcw    = (const float*)d_in[12];
  const float* fcb    = (const float*)d_in[13];
  float* ws  = (float*)d_ws;
  float* out = (float*)d_out;

  // Zero accumulators + flags (66 KB). Stream op: graph-capture safe.
  hipMemsetAsync(ws, 0, WS_CLEAR * sizeof(float), stream);

  static int use_coop = -1;   // -1 unknown, 1 works, 0 failed once -> chain
  if (use_coop != 0) {
    void* args[16] = {
      (void*)&text, (void*)&image, (void*)&ln_t_w, (void*)&ln_t_b,
      (void*)&ln_i_w, (void*)&ln_i_b, (void*)&Wa, (void*)&Wab,
      (void*)&Wq, (void*)&Wqb, (void*)&simw, (void*)&simb,
      (void*)&fcw, (void*)&fcb, (void*)&ws, (void*)&out
    };
    hipError_t e = hipLaunchCooperativeKernel((void*)fused, dim3(NBLK), dim3(256),
                                              args, 0, stream);
    if (e == hipSuccess) { use_coop = 1; return; }
    use_coop = 0;  // fall through to proven chain
  }

  k1_stats<<<NSLF, 256, 0, stream>>>(text, image, ln_t_w, ln_t_b, ln_i_w, ln_i_b, ws);
  kR_reduce<<<257, 256, 0, stream>>>(ws);
  k2_gates<<<HH*HDD/4, 256, 0, stream>>>(Wa, Wab, Wq, Wqb, simw, simb, fcw, ws);
  k3_blend<<<NROW/4, 256, 0, stream>>>(text, image, ln_t_w, ln_t_b, ln_i_w, ln_i_b, fcb, ws, out);
}

// Round 5
// 244.035 us; speedup vs baseline: 1.0178x; 1.0178x over previous
//
#include <hip/hip_runtime.h>
#include <math.h>

// Problem constants (B,S,D,H) = (8, 2048, 1024, 4), HD = 256
#define BB 8
#define SS 2048
#define DD 1024
#define HH 4
#define HDD 256
#define NROW (BB*SS)           // 16384

// ---------------- fused (cooperative) config ----------------
#define GG 32                  // rows per block
#define NBLK (NROW/GG)         // 512 blocks -> 2 blocks/CU co-resident (proven)

// fused ws layout (float offsets), ~4.3 MB
#define OFF_LOGIT 0                    // [B]
#define OFF_CNT   8                    // 3 ints (c1,c2,c3)
#define HDRCLR    16                   // floats memset to 0 per launch
#define OFF_TG    16                   // [B][D] reduced text-global
#define OFF_IG    (OFF_TG + BB*DD)
#define OFF_SIM   (OFF_IG + BB*DD)     // [B]
#define OFF_PT    32768                // [NBLK][D] per-block partials
#define OFF_PI    (OFF_PT + NBLK*DD)
#define OFF_PS    (OFF_PI + NBLK*DD)   // [NBLK]

// ---------------- fallback chain config (proven 241.6us) ----------------
#define GF 8
#define NSLF (NROW/GF)         // 2048
#define F_MU_T 0
#define F_RS_T NROW
#define F_MU_I (2*NROW)
#define F_RS_I (3*NROW)
#define F_PT   (4*NROW)
#define F_PI   (F_PT + NSLF*DD)
#define F_PS   (F_PI + NSLF*DD)
#define F_TG   (F_PS + NSLF)
#define F_IG   (F_TG + BB*DD)
#define F_SIM  (F_IG + BB*DD)
#define F_LOGIT (F_SIM + BB)

__device__ __forceinline__ float wred(float v) {
#pragma unroll
  for (int m = 32; m > 0; m >>= 1) v += __shfl_xor(v, m, 64);
  return v;
}
__device__ __forceinline__ float hsum(const float4 v) { return v.x+v.y+v.z+v.w; }
__device__ __forceinline__ float hsq(const float4 v)  { return v.x*v.x+v.y*v.y+v.z*v.z+v.w*v.w; }
__device__ __forceinline__ float hdot(const float4 a, const float4 b) {
  return a.x*b.x + a.y*b.y + a.z*b.z + a.w*b.w;
}
__device__ __forceinline__ void ast(float* p, float v) {
  __hip_atomic_store(p, v, __ATOMIC_RELAXED, __HIP_MEMORY_SCOPE_AGENT);
}

// =====================================================================
// Fused cooperative kernel, flag barriers, NO bulk atomics.
//   Phase 1 (512 blocks): wave-per-row stats, LDS-combine, write-through
//            per-block partials (8KB each, unique addrs).  arrive c1==512.
//   Reduce (blocks 0..256): spin c1, sum 64 partials/batch -> TG/IG/SIM.
//            arrive c2==257.
//   Gates  (blocks 0..255): spin c2, dot TG/IG with Wa/Wq, 8 LOGIT atomics.
//            arrive c3==256.
//   Blend  (all): prefetch rows, spin c3, sigmoid, blend (stats in LDS).
// =====================================================================
__global__ __launch_bounds__(256, 2) void fused(
    const float* __restrict__ text, const float* __restrict__ image,
    const float* __restrict__ wt, const float* __restrict__ bt,
    const float* __restrict__ wi, const float* __restrict__ bi,
    const float* __restrict__ Wa, const float* __restrict__ Wab,
    const float* __restrict__ Wq, const float* __restrict__ Wqb,
    const float* __restrict__ simw, const float* __restrict__ simb,
    const float* __restrict__ fcw, const float* __restrict__ fcb,
    float* __restrict__ ws, float* __restrict__ out)
{
  const int blk  = blockIdx.x;
  const int tid  = threadIdx.x;
  const int lane = tid & 63;
  const int wv   = tid >> 6;
  const int row0 = blk * GG;
  const int b    = blk >> 6;           // 64 blocks per batch

  __shared__ float smu_t[GG], srs_t[GG], smu_i[GG], srs_i[GG];
  __shared__ float sAcc[2][4][DD];     // 32 KB: per-wave global partial combine
  __shared__ float ssim[4];
  __shared__ float red3[4][4][BB];     // gates
  __shared__ float sred[2][8][32];     // reduce phase

  int* c1 = (int*)(ws + OFF_CNT);
  int* c2 = c1 + 1;
  int* c3 = c1 + 2;

  // ---------------- Phase 1: wave-per-row stats, prefetched ----------------
  {
    const int cb = lane << 2;          // col base within each 256-col chunk
    float4 Wt[4], Bt[4], Wi4[4], Bi4[4];
#pragma unroll
    for (int j = 0; j < 4; ++j) {
      Wt[j]  = *(const float4*)(wt + j*256 + cb);
      Bt[j]  = *(const float4*)(bt + j*256 + cb);
      Wi4[j] = *(const float4*)(wi + j*256 + cb);
      Bi4[j] = *(const float4*)(bi + j*256 + cb);
    }
    float4 tga[4], iga[4];
#pragma unroll
    for (int j = 0; j < 4; ++j) {
      tga[j] = make_float4(0.f,0.f,0.f,0.f);
      iga[j] = make_float4(0.f,0.f,0.f,0.f);
    }
    float sim_loc = 0.f;
    const float invD = 1.f/DD;
    const int rbase = row0 + wv*8;     // this wave's 8 rows

    float4 tb[2][4], ib[2][4];         // double-buffered row registers
    {
      const float* tr = text  + (size_t)rbase*DD + cb;
      const float* ir = image + (size_t)rbase*DD + cb;
#pragma unroll
      for (int j = 0; j < 4; ++j) {
        tb[0][j] = *(const float4*)(tr + j*256);
        ib[0][j] = *(const float4*)(ir + j*256);
      }
    }

#pragma unroll 2
    for (int r = 0; r < 8; ++r) {
      const int cur = r & 1, nxt = cur ^ 1;   // compile-time after unroll 2
      if (r < 7) {                     // prefetch next row under this row's work
        const float* tr = text  + (size_t)(rbase + r + 1)*DD + cb;
        const float* ir = image + (size_t)(rbase + r + 1)*DD + cb;
#pragma unroll
        for (int j = 0; j < 4; ++j) {
          tb[nxt][j] = *(const float4*)(tr + j*256);
          ib[nxt][j] = *(const float4*)(ir + j*256);
        }
      }

      float st=0.f, qt=0.f, si=0.f, qi=0.f;
#pragma unroll
      for (int j = 0; j < 4; ++j) {
        st += hsum(tb[cur][j]);  qt += hsq(tb[cur][j]);
        si += hsum(ib[cur][j]);  qi += hsq(ib[cur][j]);
      }
      st = wred(st); qt = wred(qt); si = wred(si); qi = wred(qi);
      const float mt = st*invD, rt = rsqrtf(qt*invD - mt*mt + 1e-5f);
      const float mi = si*invD, ri = rsqrtf(qi*invD - mi*mi + 1e-5f);
      if (lane == 0) {
        smu_t[wv*8+r]=mt; srs_t[wv*8+r]=rt;
        smu_i[wv*8+r]=mi; srs_i[wv*8+r]=ri;
      }

      float dot=0.f, nt=0.f, ni=0.f;
#pragma unroll
      for (int j = 0; j < 4; ++j) {
        float4 tn, iv;
        tn.x = (tb[cur][j].x-mt)*rt*Wt[j].x + Bt[j].x;
        tn.y = (tb[cur][j].y-mt)*rt*Wt[j].y + Bt[j].y;
        tn.z = (tb[cur][j].z-mt)*rt*Wt[j].z + Bt[j].z;
        tn.w = (tb[cur][j].w-mt)*rt*Wt[j].w + Bt[j].w;
        iv.x = (ib[cur][j].x-mi)*ri*Wi4[j].x + Bi4[j].x;
        iv.y = (ib[cur][j].y-mi)*ri*Wi4[j].y + Bi4[j].y;
        iv.z = (ib[cur][j].z-mi)*ri*Wi4[j].z + Bi4[j].z;
        iv.w = (ib[cur][j].w-mi)*ri*Wi4[j].w + Bi4[j].w;
        tga[j].x += tn.x; tga[j].y += tn.y; tga[j].z += tn.z; tga[j].w += tn.w;
        iga[j].x += iv.x; iga[j].y += iv.y; iga[j].z += iv.z; iga[j].w += iv.w;
        dot += hdot(tn, iv); nt += hsq(tn); ni += hsq(iv);
      }
      dot = wred(dot); nt = wred(nt); ni = wred(ni);
      sim_loc += dot / (fmaxf(sqrtf(nt),1e-6f) * fmaxf(sqrtf(ni),1e-6f));
    }

    // Block-combine per-wave global partials in LDS.
#pragma unroll
    for (int j = 0; j < 4; ++j) {
      *(float4*)&sAcc[0][wv][j*256 + cb] = tga[j];
      *(float4*)&sAcc[1][wv][j*256 + cb] = iga[j];
    }
    if (lane == 0) ssim[wv] = sim_loc;
    __syncthreads();

    const int c0 = tid << 2;
    float4 vt = make_float4(0.f,0.f,0.f,0.f);
    float4 vi = make_float4(0.f,0.f,0.f,0.f);
#pragma unroll
    for (int w = 0; w < 4; ++w) {
      const float4 a = *(const float4*)&sAcc[0][w][c0];
      vt.x += a.x; vt.y += a.y; vt.z += a.z; vt.w += a.w;
      const float4 e = *(const float4*)&sAcc[1][w][c0];
      vi.x += e.x; vi.y += e.y; vi.z += e.z; vi.w += e.w;
    }
    // Write-through per-block partials (unique addresses, agent-visible).
    float* pt = ws + OFF_PT + (size_t)blk*DD + c0;
    float* pi = ws + OFF_PI + (size_t)blk*DD + c0;
    ast(pt+0, vt.x); ast(pt+1, vt.y); ast(pt+2, vt.z); ast(pt+3, vt.w);
    ast(pi+0, vi.x); ast(pi+1, vi.y); ast(pi+2, vi.z); ast(pi+3, vi.w);
    if (tid == 0) ast(ws + OFF_PS + blk, ssim[0]+ssim[1]+ssim[2]+ssim[3]);
  }

  __syncthreads();                     // all stores drained (vmcnt) before signal
  if (tid == 0) {
    __hip_atomic_fetch_add(c1, 1, __ATOMIC_RELEASE, __HIP_MEMORY_SCOPE_AGENT);
  }

  // ---------------- Reduce (blocks 0..256) ----------------
  if (blk < 256) {
    if (tid == 0) {
      while (__hip_atomic_load(c1, __ATOMIC_RELAXED, __HIP_MEMORY_SCOPE_AGENT) < NBLK)
        __builtin_amdgcn_s_sleep(8);
      __threadfence();
    }
    __syncthreads();

    const int b2  = blk >> 5;          // 0..7 batch
    const int ch  = blk & 31;          // 32-col chunk
    const int cl  = tid & 31;
    const int sg  = tid >> 5;          // 0..7 slice-group (8 slices each)
    const int col = ch*32 + cl;
    const float* pt = ws + OFF_PT + (size_t)(b2*64 + sg*8)*DD + col;
    const float* pi = ws + OFF_PI + (size_t)(b2*64 + sg*8)*DD + col;
    float at = 0.f, ai = 0.f;
#pragma unroll
    for (int k = 0; k < 8; ++k) {
      at += pt[(size_t)k*DD];
      ai += pi[(size_t)k*DD];
    }
    sred[0][sg][cl] = at;
    sred[1][sg][cl] = ai;
    __syncthreads();
    if (tid < 32) {
      float v = 0.f;
#pragma unroll
      for (int q = 0; q < 8; ++q) v += sred[0][q][tid];
      ast(&ws[OFF_TG + b2*DD + ch*32 + tid], v);
    } else if (tid < 64) {
      const int c = tid - 32;
      float v = 0.f;
#pragma unroll
      for (int q = 0; q < 8; ++q) v += sred[1][q][c];
      ast(&ws[OFF_IG + b2*DD + ch*32 + c], v);
    }
    __syncthreads();
    if (tid == 0) {
      __hip_atomic_fetch_add(c2, 1, __ATOMIC_RELEASE, __HIP_MEMORY_SCOPE_AGENT);
    }
  } else if (blk == 256) {
    if (tid == 0) {
      while (__hip_atomic_load(c1, __ATOMIC_RELAXED, __HIP_MEMORY_SCOPE_AGENT) < NBLK)
        __builtin_amdgcn_s_sleep(8);
      __threadfence();
    }
    __syncthreads();
    float* sflat = (float*)sred;
    const int b3 = tid >> 5, j = tid & 31;
    const float a = ws[OFF_PS + b3*64 + j*2] + ws[OFF_PS + b3*64 + j*2 + 1];
    sflat[tid] = a;
    __syncthreads();
    if (j == 0) {
      float s = 0.f;
#pragma unroll
      for (int m = 0; m < 32; ++m) s += sflat[b3*32 + m];
      ast(&ws[OFF_SIM + b3], s);
    }
    __syncthreads();
    if (tid == 0) {
      __hip_atomic_fetch_add(c2, 1, __ATOMIC_RELEASE, __HIP_MEMORY_SCOPE_AGENT);
    }
  }

  // ---------------- Gates (blocks 0..255) ----------------
  if (blk < 256) {
    if (tid == 0) {
      while (__hip_atomic_load(c2, __ATOMIC_RELAXED, __HIP_MEMORY_SCOPE_AGENT) < 257)
        __builtin_amdgcn_s_sleep(8);
      __threadfence();
    }
    __syncthreads();

    const int d0 = tid << 2;
    const int r0 = blk * 4;            // flat (h,k) row base, 0..1023
    for (int rr = 0; rr < 4; ++rr) {
      const int r = r0 + rr;
      const float4 a4 = *(const float4*)(Wa + (size_t)r*DD + d0);
      const float4 q4 = *(const float4*)(Wq + (size_t)r*DD + d0);
      float acc[BB];
#pragma unroll
      for (int bq = 0; bq < BB; ++bq) {
        const float4 t = *(const float4*)(ws + OFF_TG + bq*DD + d0);
        const float4 i = *(const float4*)(ws + OFF_IG + bq*DD + d0);
        acc[bq] = hdot(a4, t) + hdot(q4, i);
      }
#pragma unroll
      for (int bq = 0; bq < BB; ++bq) {
        acc[bq] = wred(acc[bq]);
        if (lane == 0) red3[rr][wv][bq] = acc[bq];
      }
    }
    __syncthreads();
    if (tid < BB) {
      const int bq = tid;
      const float inv = 1.f/SS;
      const float gs = ws[OFF_SIM + bq] * inv;
      float part = 0.f;
#pragma unroll
      for (int rr = 0; rr < 4; ++rr) {
        const int r = r0 + rr;
        const int k = r & 255;
        const float v = (red3[rr][0][bq] + red3[rr][1][bq] + red3[rr][2][bq] + red3[rr][3][bq]) * inv;
        float gate = v + Wab[r] + Wqb[r] + gs*simw[k] + simb[k];
        gate = fmaxf(gate, 0.f);
        part += gate * fcw[r];
      }
      atomicAdd(&ws[OFF_LOGIT + bq], part);
    }
    __syncthreads();                   // drain LOGIT atomics before signal
    if (tid == 0) {
      __hip_atomic_fetch_add(c3, 1, __ATOMIC_RELEASE, __HIP_MEMORY_SCOPE_AGENT);
    }
  }

  // ---------------- Blend (all blocks) ----------------
  {
    const int d0 = tid << 2;
    // Prefetch first row-group + LN params BEFORE the final spin.
    const float4 wt4 = *(const float4*)(wt + d0);
    const float4 bt4 = *(const float4*)(bt + d0);
    const float4 wi4 = *(const float4*)(wi + d0);
    const float4 bi4 = *(const float4*)(bi + d0);
    float4 tg[2][4], ig[2][4];
#pragma unroll
    for (int r = 0; r < 4; ++r) {
      tg[0][r] = *(const float4*)(text  + (size_t)(row0+r)*DD + d0);
      ig[0][r] = *(const float4*)(image + (size_t)(row0+r)*DD + d0);
    }

    if (tid == 0) {
      while (__hip_atomic_load(c3, __ATOMIC_RELAXED, __HIP_MEMORY_SCOPE_AGENT) < 256)
        __builtin_amdgcn_s_sleep(8);
      __threadfence();
    }
    __syncthreads();

    const float g  = 1.f / (1.f + expf(-(ws[OFF_LOGIT + b] + fcb[0])));
    const float gi = 1.f - g;

#pragma unroll 2
    for (int gidx = 0; gidx < 8; ++gidx) {
      const int cur = gidx & 1, nxt = cur ^ 1;
      if (gidx < 7) {
        const int nr = row0 + (gidx+1)*4;
#pragma unroll
        for (int r = 0; r < 4; ++r) {
          tg[nxt][r] = *(const float4*)(text  + (size_t)(nr+r)*DD + d0);
          ig[nxt][r] = *(const float4*)(image + (size_t)(nr+r)*DD + d0);
        }
      }
      const int rr = gidx*4;
#pragma unroll
      for (int r = 0; r < 4; ++r) {
        const float mt = smu_t[rr+r], rt = srs_t[rr+r];
        const float mi = smu_i[rr+r], ri = srs_i[rr+r];
        const float gt = g*rt, gii = gi*ri;
        float4 o;
        o.x = gt*(tg[cur][r].x-mt)*wt4.x + g*bt4.x + gii*(ig[cur][r].x-mi)*wi4.x + gi*bi4.x;
        o.y = gt*(tg[cur][r].y-mt)*wt4.y + g*bt4.y + gii*(ig[cur][r].y-mi)*wi4.y + gi*bi4.y;
        o.z = gt*(tg[cur][r].z-mt)*wt4.z + g*bt4.z + gii*(ig[cur][r].z-mi)*wi4.z + gi*bi4.z;
        o.w = gt*(tg[cur][r].w-mt)*wt4.w + g*bt4.w + gii*(ig[cur][r].w-mi)*wi4.w + gi*bi4.w;
        *(float4*)(out + (size_t)(row0+rr+r)*DD + d0) = o;
      }
    }
  }
}

// =====================================================================
// Fallback chain (proven 241.6 us) — only used if coop launch fails.
// =====================================================================
__global__ __launch_bounds__(256) void k1_stats(
    const float* __restrict__ text, const float* __restrict__ image,
    const float* __restrict__ wt, const float* __restrict__ bt,
    const float* __restrict__ wi, const float* __restrict__ bi,
    float* __restrict__ ws)
{
  const int g    = blockIdx.x;
  const int tid  = threadIdx.x;
  const int lane = tid & 63;
  const int wv   = tid >> 6;
  const int d0   = tid << 2;
  const int row0 = g * GF;

  __shared__ float red1[4][8];
  __shared__ float red2[4][6];

  const float4 wt4 = *(const float4*)(wt + d0);
  const float4 bt4 = *(const float4*)(bt + d0);
  const float4 wi4 = *(const float4*)(wi + d0);
  const float4 bi4 = *(const float4*)(bi + d0);

  float4 tga = make_float4(0.f,0.f,0.f,0.f);
  float4 iga = make_float4(0.f,0.f,0.f,0.f);
  float sim_loc = 0.f;

  for (int r = 0; r < GF; r += 2) {
    const size_t base0 = (size_t)(row0 + r) * DD + d0;
    const size_t base1 = base0 + DD;
    const float4 t0 = *(const float4*)(text  + base0);
    const float4 i0 = *(const float4*)(image + base0);
    const float4 t1 = *(const float4*)(text  + base1);
    const float4 i1 = *(const float4*)(image + base1);

    float a0 = hsum(t0), a1 = hsq(t0), a2 = hsum(i0), a3 = hsq(i0);
    float a4 = hsum(t1), a5 = hsq(t1), a6 = hsum(i1), a7 = hsq(i1);
    a0 = wred(a0); a1 = wred(a1); a2 = wred(a2); a3 = wred(a3);
    a4 = wred(a4); a5 = wred(a5); a6 = wred(a6); a7 = wred(a7);
    if (lane == 0) {
      red1[wv][0]=a0; red1[wv][1]=a1; red1[wv][2]=a2; red1[wv][3]=a3;
      red1[wv][4]=a4; red1[wv][5]=a5; red1[wv][6]=a6; red1[wv][7]=a7;
    }
    __syncthreads();
    float s[8];
#pragma unroll
    for (int q = 0; q < 8; ++q) s[q] = red1[0][q]+red1[1][q]+red1[2][q]+red1[3][q];
    const float invD = 1.f/DD;
    const float mt0 = s[0]*invD, rt0 = rsqrtf(s[1]*invD - mt0*mt0 + 1e-5f);
    const float mi0 = s[2]*invD, ri0 = rsqrtf(s[3]*invD - mi0*mi0 + 1e-5f);
    const float mt1 = s[4]*invD, rt1 = rsqrtf(s[5]*invD - mt1*mt1 + 1e-5f);
    const float mi1 = s[6]*invD, ri1 = rsqrtf(s[7]*invD - mi1*mi1 + 1e-5f);
    if (tid == 0) {
      const int row = row0 + r;
      ws[F_MU_T+row]=mt0;   ws[F_RS_T+row]=rt0;
      ws[F_MU_I+row]=mi0;   ws[F_RS_I+row]=ri0;
      ws[F_MU_T+row+1]=mt1; ws[F_RS_T+row+1]=rt1;
      ws[F_MU_I+row+1]=mi1; ws[F_RS_I+row+1]=ri1;
    }
    float4 tn0, in0, tn1, in1;
    tn0.x = (t0.x-mt0)*rt0*wt4.x + bt4.x;  tn0.y = (t0.y-mt0)*rt0*wt4.y + bt4.y;
    tn0.z = (t0.z-mt0)*rt0*wt4.z + bt4.z;  tn0.w = (t0.w-mt0)*rt0*wt4.w + bt4.w;
    in0.x = (i0.x-mi0)*ri0*wi4.x + bi4.x;  in0.y = (i0.y-mi0)*ri0*wi4.y + bi4.y;
    in0.z = (i0.z-mi0)*ri0*wi4.z + bi4.z;  in0.w = (i0.w-mi0)*ri0*wi4.w + bi4.w;
    tn1.x = (t1.x-mt1)*rt1*wt4.x + bt4.x;  tn1.y = (t1.y-mt1)*rt1*wt4.y + bt4.y;
    tn1.z = (t1.z-mt1)*rt1*wt4.z + bt4.z;  tn1.w = (t1.w-mt1)*rt1*wt4.w + bt4.w;
    in1.x = (i1.x-mi1)*ri1*wi4.x + bi4.x;  in1.y = (i1.y-mi1)*ri1*wi4.y + bi4.y;
    in1.z = (i1.z-mi1)*ri1*wi4.z + bi4.z;  in1.w = (i1.w-mi1)*ri1*wi4.w + bi4.w;

    tga.x += tn0.x + tn1.x; tga.y += tn0.y + tn1.y;
    tga.z += tn0.z + tn1.z; tga.w += tn0.w + tn1.w;
    iga.x += in0.x + in1.x; iga.y += in0.y + in1.y;
    iga.z += in0.z + in1.z; iga.w += in0.w + in1.w;

    float b0 = hdot(tn0,in0), b1 = hsq(tn0), b2 = hsq(in0);
    float b3 = hdot(tn1,in1), b4 = hsq(tn1), b5 = hsq(in1);
    b0 = wred(b0); b1 = wred(b1); b2 = wred(b2);
    b3 = wred(b3); b4 = wred(b4); b5 = wred(b5);
    if (lane == 0) {
      red2[wv][0]=b0; red2[wv][1]=b1; red2[wv][2]=b2;
      red2[wv][3]=b3; red2[wv][4]=b4; red2[wv][5]=b5;
    }
    __syncthreads();
    if (tid == 0) {
      float u[6];
#pragma unroll
      for (int q = 0; q < 6; ++q) u[q] = red2[0][q]+red2[1][q]+red2[2][q]+red2[3][q];
      sim_loc += u[0] / (fmaxf(sqrtf(u[1]),1e-6f) * fmaxf(sqrtf(u[2]),1e-6f));
      sim_loc += u[3] / (fmaxf(sqrtf(u[4]),1e-6f) * fmaxf(sqrtf(u[5]),1e-6f));
    }
  }
  *(float4*)(ws + F_PT + (size_t)g*DD + d0) = tga;
  *(float4*)(ws + F_PI + (size_t)g*DD + d0) = iga;
  if (tid == 0) ws[F_PS + g] = sim_loc;
}

__global__ __launch_bounds__(256) void kR_reduce(float* __restrict__ ws)
{
  const int tid = threadIdx.x;
  if (blockIdx.x < 256) {
    const int b   = blockIdx.x >> 5;
    const int ch  = blockIdx.x & 31;
    const int cl  = tid & 31;
    const int sg  = tid >> 5;
    const int col = ch*32 + cl;
    const float* pt = ws + F_PT + (size_t)(b*256 + sg*32)*DD + col;
    const float* pi = ws + F_PI + (size_t)(b*256 + sg*32)*DD + col;
    float at = 0.f, ai = 0.f;
#pragma unroll 4
    for (int k = 0; k < 32; ++k) {
      at += pt[(size_t)k*DD];
      ai += pi[(size_t)k*DD];
    }
    __shared__ float sred[2][8][32];
    sred[0][sg][cl] = at;
    sred[1][sg][cl] = ai;
    __syncthreads();
    if (tid < 32) {
      float v = 0.f;
#pragma unroll
      for (int q = 0; q < 8; ++q) v += sred[0][q][tid];
      ws[F_TG + b*DD + ch*32 + tid] = v;
    } else if (tid < 64) {
      const int c = tid - 32;
      float v = 0.f;
#pragma unroll
      for (int q = 0; q < 8; ++q) v += sred[1][q][c];
      ws[F_IG + b*DD + ch*32 + c] = v;
    }
  } else {
    __shared__ float sred[256];
    const int b = tid >> 5, j = tid & 31;
    float a = 0.f;
#pragma unroll
    for (int k = 0; k < 8; ++k) a += ws[F_PS + b*256 + j*8 + k];
    sred[tid] = a;
    __syncthreads();
    if (j == 0) {
      float s = 0.f;
#pragma unroll
      for (int m = 0; m < 32; ++m) s += sred[b*32 + m];
      ws[F_SIM + b] = s;
    }
    if (tid < BB) ws[F_LOGIT + tid] = 0.f;
  }
}

__global__ __launch_bounds__(256) void k2_gates(
    const float* __restrict__ Wa, const float* __restrict__ Wab,
    const float* __restrict__ Wq, const float* __restrict__ Wqb,
    const float* __restrict__ simw, const float* __restrict__ simb,
    const float* __restrict__ fcw, float* __restrict__ ws)
{
  const int tid  = threadIdx.x;
  const int lane = tid & 63;
  const int wv   = tid >> 6;
  const int r0   = blockIdx.x * 4;
  const int d0   = tid << 2;

  __shared__ float red[4][4][BB];

  for (int rr = 0; rr < 4; ++rr) {
    const int r = r0 + rr;
    const float4 a4 = *(const float4*)(Wa + (size_t)r*DD + d0);
    const float4 q4 = *(const float4*)(Wq + (size_t)r*DD + d0);
    float acc[BB];
#pragma unroll
    for (int b = 0; b < BB; ++b) {
      const float4 t = *(const float4*)(ws + F_TG + b*DD + d0);
      const float4 i = *(const float4*)(ws + F_IG + b*DD + d0);
      acc[b] = hdot(a4, t) + hdot(q4, i);
    }
#pragma unroll
    for (int b = 0; b < BB; ++b) {
      acc[b] = wred(acc[b]);
      if (lane == 0) red[rr][wv][b] = acc[b];
    }
  }
  __syncthreads();
  if (tid < BB) {
    const int b = tid;
    const float inv = 1.f/SS;
    const float gs = ws[F_SIM + b] * inv;
    float part = 0.f;
#pragma unroll
    for (int rr = 0; rr < 4; ++rr) {
      const int r = r0 + rr;
      const int k = r & 255;
      const float v = (red[rr][0][b] + red[rr][1][b] + red[rr][2][b] + red[rr][3][b]) * inv;
      float gate = v + Wab[r] + Wqb[r] + gs*simw[k] + simb[k];
      gate = fmaxf(gate, 0.f);
      part += gate * fcw[r];
    }
    atomicAdd(&ws[F_LOGIT + b], part);
  }
}

__global__ __launch_bounds__(256) void k3_blend(
    const float* __restrict__ text, const float* __restrict__ image,
    const float* __restrict__ wt, const float* __restrict__ bt,
    const float* __restrict__ wi, const float* __restrict__ bi,
    const float* __restrict__ fcb,
    const float* __restrict__ ws, float* __restrict__ out)
{
  const int r0 = blockIdx.x * 4;
  const int b  = r0 >> 11;
  const int d0 = threadIdx.x << 2;

  float4 t[4], im[4];
#pragma unroll
  for (int r = 0; r < 4; ++r) {
    t[r]  = *(const float4*)(text  + (size_t)(r0+r)*DD + d0);
    im[r] = *(const float4*)(image + (size_t)(r0+r)*DD + d0);
  }
  const float4 wt4 = *(const float4*)(wt + d0);
  const float4 bt4 = *(const float4*)(bt + d0);
  const float4 wi4 = *(const float4*)(wi + d0);
  const float4 bi4 = *(const float4*)(bi + d0);

  const float g  = 1.f / (1.f + expf(-(ws[F_LOGIT+b] + fcb[0])));
  const float gi = 1.f - g;

#pragma unroll
  for (int r = 0; r < 4; ++r) {
    const float mt = ws[F_MU_T+r0+r], rt = ws[F_RS_T+r0+r];
    const float mi = ws[F_MU_I+r0+r], ri = ws[F_RS_I+r0+r];
    const float gt = g*rt, gii = gi*ri;
    float4 o;
    o.x = gt*(t[r].x-mt)*wt4.x + g*bt4.x + gii*(im[r].x-mi)*wi4.x + gi*bi4.x;
    o.y = gt*(t[r].y-mt)*wt4.y + g*bt4.y + gii*(im[r].y-mi)*wi4.y + gi*bi4.y;
    o.z = gt*(t[r].z-mt)*wt4.z + g*bt4.z + gii*(im[r].z-mi)*wi4.z + gi*bi4.z;
    o.w = gt*(t[r].w-mt)*wt4.w + g*bt4.w + gii*(im[r].w-mi)*wi4.w + gi*bi4.w;
    *(float4*)(out + (size_t)(r0+r)*DD + d0) = o;
  }
}

extern "C" void kernel_launch(void* const* d_in, const int* in_sizes, int n_in,
                              void* d_out, int out_size, void* d_ws, size_t ws_size,
                              hipStream_t stream)
{
  const float* text   = (const float*)d_in[0];
  const float* image  = (const float*)d_in[1];
  const float* ln_t_w = (const float*)d_in[2];
  const float* ln_t_b = (const float*)d_in[3];
  const float* ln_i_w = (const float*)d_in[4];
  const float* ln_i_b = (const float*)d_in[5];
  const float* Wa     = (const float*)d_in[6];
  const float* Wab    = (const float*)d_in[7];
  const float* Wq     = (const float*)d_in[8];
  const float* Wqb    = (const float*)d_in[9];
  const float* simw   = (const float*)d_in[10];
  const float* simb   = (const float*)d_in[11];
  const float* fcw    = (const float*)d_in[12];
  const float* fcb    = (const float*)d_in[13];
  float* ws  = (float*)d_ws;
  float* out = (float*)d_out;

  // Zero LOGIT + barrier counters only (64 B). Stream op: graph-capture safe.
  hipMemsetAsync(ws, 0, HDRCLR * sizeof(float), stream);

  static int use_coop = -1;   // -1 unknown, 1 works, 0 failed once -> chain
  if (use_coop != 0) {
    void* args[16] = {
      (void*)&text, (void*)&image, (void*)&ln_t_w, (void*)&ln_t_b,
      (void*)&ln_i_w, (void*)&ln_i_b, (void*)&Wa, (void*)&Wab,
      (void*)&Wq, (void*)&Wqb, (void*)&simw, (void*)&simb,
      (void*)&fcw, (void*)&fcb, (void*)&ws, (void*)&out
    };
    hipError_t e = hipLaunchCooperativeKernel((void*)fused, dim3(NBLK), dim3(256),
                                              args, 0, stream);
    if (e == hipSuccess) { use_coop = 1; return; }
    use_coop = 0;  // fall through to proven chain
  }

  k1_stats<<<NSLF, 256, 0, stream>>>(text, image, ln_t_w, ln_t_b, ln_i_w, ln_i_b, ws);
  kR_reduce<<<257, 256, 0, stream>>>(ws);
  k2_gates<<<HH*HDD/4, 256, 0, stream>>>(Wa, Wab, Wq, Wqb, simw, simb, fcw, ws);
  k3_blend<<<NROW/4, 256, 0, stream>>>(text, image, ln_t_w, ln_t_b, ln_i_w, ln_i_b, fcb, ws, out);
}